// Round 1
// baseline (381.409 us; speedup 1.0000x reference)
//
#include <hip/hip_runtime.h>
#include <stdint.h>

#define D_IN  128
#define D_OUT 64
#define BN_EPS 1e-3f

#define BIN_SHIFT 6
#define BIN_NODES 64           // 1 << BIN_SHIFT
#define BIN_CAP   2560         // avg 2048 records/bin, +11 sigma headroom
#define CHUNK     8192         // edges per partition block (391 blocks)
#define MAX_BINS  1600

typedef __attribute__((ext_vector_type(8))) short bf16x8;
typedef __attribute__((ext_vector_type(4))) float f32x4;

__device__ __forceinline__ ushort f32_to_bf16_rne(float f) {
  uint u = __float_as_uint(f);
  u += 0x7FFFu + ((u >> 16) & 1u);
  return (ushort)(u >> 16);
}
__device__ __forceinline__ float bf16_to_f32(ushort h) {
  return __uint_as_float((uint)h << 16);
}

// ------------- GEMM via MFMA: pre16 = bf16(X @ W), bf16 in / fp32 acc -------
// OUTPUT LAYOUT: quarter-major. pre16[q * (n_nodes*16) + row*16 + m] holds
// channel q*16+m of `row`. Each 16-channel slab is 3.2 MB (fits per-XCD L2),
// which is what the phased gather kernel relies on.
__global__ __launch_bounds__(256) void gemm_mfma_kernel(
    const float* __restrict__ x, const float* __restrict__ W,
    ushort* __restrict__ pre16, int n_nodes, int n_tiles) {
  __shared__ ushort Wb[D_IN * D_OUT];  // 16 KB bf16 copy of W
  const int t = threadIdx.x;
  for (int i = t; i < D_IN * D_OUT; i += 256) Wb[i] = f32_to_bf16_rne(W[i]);
  __syncthreads();

  const int lane = t & 63;
  const int wave = t >> 6;
  const int m = lane & 15;
  const int quad = lane >> 4;

  bf16x8 bfrag[4][4];
#pragma unroll
  for (int nt = 0; nt < 4; ++nt)
#pragma unroll
    for (int s = 0; s < 4; ++s)
#pragma unroll
      for (int j = 0; j < 8; ++j)
        bfrag[nt][s][j] =
            (short)Wb[(32 * s + quad * 8 + j) * D_OUT + nt * 16 + m];

  const size_t slab = (size_t)n_nodes * 16;

  for (int tile = blockIdx.x; tile < n_tiles; tile += gridDim.x) {
    const int rbase = tile * 64 + wave * 16;
    const int row = rbase + m;
    const size_t rl = (size_t)min(row, n_nodes - 1);
    f32x4 acc0 = {0.f, 0.f, 0.f, 0.f}, acc1 = {0.f, 0.f, 0.f, 0.f};
    f32x4 acc2 = {0.f, 0.f, 0.f, 0.f}, acc3 = {0.f, 0.f, 0.f, 0.f};
#pragma unroll
    for (int s = 0; s < 4; ++s) {
      const float4 xa = *(const float4*)&x[rl * D_IN + s * 32 + quad * 8];
      const float4 xb = *(const float4*)&x[rl * D_IN + s * 32 + quad * 8 + 4];
      bf16x8 af;
      af[0] = (short)f32_to_bf16_rne(xa.x);
      af[1] = (short)f32_to_bf16_rne(xa.y);
      af[2] = (short)f32_to_bf16_rne(xa.z);
      af[3] = (short)f32_to_bf16_rne(xa.w);
      af[4] = (short)f32_to_bf16_rne(xb.x);
      af[5] = (short)f32_to_bf16_rne(xb.y);
      af[6] = (short)f32_to_bf16_rne(xb.z);
      af[7] = (short)f32_to_bf16_rne(xb.w);
      acc0 = __builtin_amdgcn_mfma_f32_16x16x32_bf16(af, bfrag[0][s], acc0, 0, 0, 0);
      acc1 = __builtin_amdgcn_mfma_f32_16x16x32_bf16(af, bfrag[1][s], acc1, 0, 0, 0);
      acc2 = __builtin_amdgcn_mfma_f32_16x16x32_bf16(af, bfrag[2][s], acc2, 0, 0, 0);
      acc3 = __builtin_amdgcn_mfma_f32_16x16x32_bf16(af, bfrag[3][s], acc3, 0, 0, 0);
    }
#pragma unroll
    for (int reg = 0; reg < 4; ++reg) {
      const int r = rbase + quad * 4 + reg;
      if (r < n_nodes) {
        ushort* po = &pre16[(size_t)r * 16 + m];
        po[0]        = f32_to_bf16_rne(acc0[reg]);
        po[slab]     = f32_to_bf16_rne(acc1[reg]);
        po[2 * slab] = f32_to_bf16_rne(acc2[reg]);
        po[3 * slab] = f32_to_bf16_rne(acc3[reg]);
      }
    }
  }
}

// ---------------- Partition: bin edges by dst>>6, x4-vectorized loads ---------
// record: w0 = (dst_low6 << 17) | src17 ; w1 = fp32 edge_val
__global__ __launch_bounds__(256) void partition_kernel(
    const float* __restrict__ ev, const int* __restrict__ esrc,
    const int* __restrict__ edst, int* __restrict__ bin_cursor,
    uint2* __restrict__ bucket, int n_edges, int n_bins) {
  __shared__ int cnt[MAX_BINS];
  __shared__ int base[MAX_BINS];
  const int t = threadIdx.x;
  const int beg = blockIdx.x * CHUNK;
  const int end = min(beg + CHUNK, n_edges);

  for (int i = t; i < n_bins; i += 256) cnt[i] = 0;
  __syncthreads();

  // phase A: histogram, 4 edges per lane per load (1 KB/wave coalesced)
  for (int i = beg + t * 4; i < end; i += 1024) {
    if (i + 3 < end) {
      const int4 d4 = *(const int4*)&edst[i];
      atomicAdd(&cnt[d4.x >> BIN_SHIFT], 1);
      atomicAdd(&cnt[d4.y >> BIN_SHIFT], 1);
      atomicAdd(&cnt[d4.z >> BIN_SHIFT], 1);
      atomicAdd(&cnt[d4.w >> BIN_SHIFT], 1);
    } else {
      for (int k = i; k < end; ++k) atomicAdd(&cnt[edst[k] >> BIN_SHIFT], 1);
    }
  }
  __syncthreads();

  // phase B: reserve contiguous space per (block, bin)
  for (int i = t; i < n_bins; i += 256) {
    const int c = cnt[i];
    int b = 0;
    if (c > 0) b = atomicAdd(&bin_cursor[i], c);
    if (b > BIN_CAP) b = BIN_CAP;
    base[i] = i * BIN_CAP + b;
    cnt[i] = 0;  // reuse as rank cursor
  }
  __syncthreads();

  // phase C: scatter records (re-reads are L2-hot from phase A)
  for (int i = beg + t * 4; i < end; i += 1024) {
    if (i + 3 < end) {
      const int4 d4 = *(const int4*)&edst[i];
      const int4 s4 = *(const int4*)&esrc[i];
      const float4 v4 = *(const float4*)&ev[i];
#pragma unroll
      for (int k = 0; k < 4; ++k) {
        const int dst = (&d4.x)[k];
        const int src = (&s4.x)[k];
        const float v = (&v4.x)[k];
        const int bin = dst >> BIN_SHIFT;
        const int r = atomicAdd(&cnt[bin], 1);
        const int pos = base[bin] + r;
        if (pos < (bin + 1) * BIN_CAP) {
          const uint w0 = ((uint)(dst & (BIN_NODES - 1)) << 17) | (uint)src;
          bucket[pos] = make_uint2(w0, __float_as_uint(v));
        }
      }
    } else {
      for (int k = i; k < end; ++k) {
        const int dst = edst[k];
        const int bin = dst >> BIN_SHIFT;
        const int r = atomicAdd(&cnt[bin], 1);
        const int pos = base[bin] + r;
        if (pos < (bin + 1) * BIN_CAP) {
          const uint w0 = ((uint)(dst & (BIN_NODES - 1)) << 17) | (uint)esrc[k];
          bucket[pos] = make_uint2(w0, __float_as_uint(ev[k]));
        }
      }
    }
  }
}

// ------- Bin sort+gather: quarter-phased for per-XCD L2 residency ------------
// Grid = 4 * n_bins, quarter-major (blocks [q*n_bins, (q+1)*n_bins) handle
// channel quarter q). Resident blocks thus share one 3.2 MB pre16 slab ->
// the random per-edge gather hits L2 instead of L3/HBM.
// Each block redoes the cheap LDS counting sort for its bin (bucket re-reads
// are L3-resident), then gathers 16 channels:
//   lane = (rsel = lane>>3: record slot 0..7, c = lane&7: channel pair).
// A wave processes 8 records per load instruction; main loop keeps 4 loads
// (32 records) in flight.
__global__ __launch_bounds__(256) void bin_sort_gather_kernel(
    const ushort* __restrict__ pre16, const uint2* __restrict__ bucket,
    const int* __restrict__ bin_cursor, float* __restrict__ out,
    float* __restrict__ stats, int n_nodes, int n_bins) {
  __shared__ uint s_src[BIN_CAP];          // 10.0 KB
  __shared__ ushort s_val[BIN_CAP];        // 5.0 KB
  __shared__ int s_hist[BIN_NODES];
  __shared__ int s_off[BIN_NODES + 1];
  __shared__ int s_cur[BIN_NODES];

  const int t = threadIdx.x;
  const int bin = blockIdx.x % n_bins;
  const int q = blockIdx.x / n_bins;       // channel quarter 0..3
  const int cnt = min(bin_cursor[bin], BIN_CAP);
  const int64_t rbase = (int64_t)bin * BIN_CAP;

  if (t < BIN_NODES) s_hist[t] = 0;
  __syncthreads();

  for (int i = t; i < cnt; i += 256)
    atomicAdd(&s_hist[bucket[rbase + i].x >> 17], 1);
  __syncthreads();

  int own = (t < BIN_NODES) ? s_hist[t] : 0;
  for (int off = 1; off < BIN_NODES; off <<= 1) {
    int u = 0;
    if (t < BIN_NODES && t >= off) u = s_hist[t - off];
    __syncthreads();
    if (t < BIN_NODES) s_hist[t] += u;
    __syncthreads();
  }
  if (t < BIN_NODES) {
    const int e = s_hist[t] - own;
    s_off[t] = e;
    s_cur[t] = e;
  }
  if (t == 0) s_off[BIN_NODES] = cnt;
  __syncthreads();

  for (int i = t; i < cnt; i += 256) {
    const uint2 r = bucket[rbase + i];
    const int d = r.x >> 17;
    const int p = atomicAdd(&s_cur[d], 1);
    s_src[p] = r.x & 0x1FFFFu;
    s_val[p] = f32_to_bf16_rne(__uint_as_float(r.y));
  }
  __syncthreads();

  // gather from this quarter's 3.2 MB slab (L2-resident)
  const ushort* __restrict__ slab = pre16 + (size_t)q * ((size_t)n_nodes * 16);
  const int lane = t & 63;
  const int wave = t >> 6;
  const int rsel = lane >> 3;   // record slot within group of 8
  const int c = lane & 7;       // channel pair 0..7 (2 channels each)
  const int node0 = bin * BIN_NODES;
  float csx = 0.f, csy = 0.f, cs2x = 0.f, cs2y = 0.f;

  for (int nl = wave; nl < BIN_NODES; nl += 4) {
    const int node = node0 + nl;
    if (node < n_nodes) {
      const int jb = s_off[nl], je = s_off[nl + 1];
      float a0x = 0.f, a0y = 0.f, a1x = 0.f, a1y = 0.f;
      float a2x = 0.f, a2y = 0.f, a3x = 0.f, a3y = 0.f;
      int base = jb;
      // main: 32 records per iteration, 4 independent loads in flight
      for (; base + 32 <= je; base += 32) {
        const int j0 = base + rsel;
        const uint src0 = s_src[j0],      src1 = s_src[j0 + 8];
        const uint src2 = s_src[j0 + 16], src3 = s_src[j0 + 24];
        const float v0 = bf16_to_f32(s_val[j0]);
        const float v1 = bf16_to_f32(s_val[j0 + 8]);
        const float v2 = bf16_to_f32(s_val[j0 + 16]);
        const float v3 = bf16_to_f32(s_val[j0 + 24]);
        const uint p0 = *(const uint*)&slab[(size_t)src0 * 16 + 2 * c];
        const uint p1 = *(const uint*)&slab[(size_t)src1 * 16 + 2 * c];
        const uint p2 = *(const uint*)&slab[(size_t)src2 * 16 + 2 * c];
        const uint p3 = *(const uint*)&slab[(size_t)src3 * 16 + 2 * c];
        a0x += v0 * bf16_to_f32((ushort)(p0 & 0xFFFFu));
        a0y += v0 * bf16_to_f32((ushort)(p0 >> 16));
        a1x += v1 * bf16_to_f32((ushort)(p1 & 0xFFFFu));
        a1y += v1 * bf16_to_f32((ushort)(p1 >> 16));
        a2x += v2 * bf16_to_f32((ushort)(p2 & 0xFFFFu));
        a2y += v2 * bf16_to_f32((ushort)(p2 >> 16));
        a3x += v3 * bf16_to_f32((ushort)(p3 & 0xFFFFu));
        a3y += v3 * bf16_to_f32((ushort)(p3 >> 16));
      }
      // tail: 8 records per iteration, per-lane predicate
      for (; base < je; base += 8) {
        const int j = base + rsel;
        if (j < je) {
          const uint src = s_src[j];
          const float v = bf16_to_f32(s_val[j]);
          const uint p = *(const uint*)&slab[(size_t)src * 16 + 2 * c];
          a0x += v * bf16_to_f32((ushort)(p & 0xFFFFu));
          a0y += v * bf16_to_f32((ushort)(p >> 16));
        }
      }
      float ax = (a0x + a1x) + (a2x + a3x);
      float ay = (a0y + a1y) + (a2y + a3y);
      // reduce across the 8 record slots (lanes stride 8)
      ax += __shfl_xor(ax, 8);
      ax += __shfl_xor(ax, 16);
      ax += __shfl_xor(ax, 32);
      ay += __shfl_xor(ay, 8);
      ay += __shfl_xor(ay, 16);
      ay += __shfl_xor(ay, 32);
      if (rsel == 0) {  // lanes 0..7: channel pairs of this quarter
        *(float2*)&out[(size_t)node * D_OUT + q * 16 + 2 * c] =
            make_float2(ax, ay);
        csx += ax;
        cs2x += ax * ax;
        csy += ay;
        cs2y += ay * ay;
      }
    }
  }
  __syncthreads();  // record reads done; alias reduction buffers onto s_src

  float* red = (float*)s_src;        // [4 waves][16 ch] sums
  float* red2 = red + 64;            // [4 waves][16 ch] sumsq
  if (rsel == 0) {
    red[wave * 16 + 2 * c] = csx;
    red[wave * 16 + 2 * c + 1] = csy;
    red2[wave * 16 + 2 * c] = cs2x;
    red2[wave * 16 + 2 * c + 1] = cs2y;
  }
  __syncthreads();
  if (t < 16) {
    float s = red[t] + red[16 + t] + red[32 + t] + red[48 + t];
    float s2 = red2[t] + red2[16 + t] + red2[32 + t] + red2[48 + t];
    atomicAdd(&stats[q * 16 + t], s);
    atomicAdd(&stats[64 + q * 16 + t], s2);
  }
}

// ---------------- Normalize + ReLU (in place, float4) ----------------
__global__ __launch_bounds__(256) void norm_kernel(
    float* __restrict__ out, const float* __restrict__ stats, int64_t n_vec4,
    float inv_n) {
  const int c = (threadIdx.x * 4) & 63;
  float mean[4], scale[4];
#pragma unroll
  for (int k = 0; k < 4; ++k) {
    mean[k] = stats[c + k] * inv_n;
    const float var = stats[64 + c + k] * inv_n - mean[k] * mean[k];
    scale[k] = rsqrtf(var + BN_EPS);
  }
  const int64_t stride = (int64_t)gridDim.x * 256;
  for (int64_t i = (int64_t)blockIdx.x * 256 + threadIdx.x; i < n_vec4;
       i += stride) {
    float4 v = ((float4*)out)[i];
    v.x = (v.x - mean[0]) * scale[0];
    v.y = (v.y - mean[1]) * scale[1];
    v.z = (v.z - mean[2]) * scale[2];
    v.w = (v.w - mean[3]) * scale[3];
    v.x = v.x > 0.f ? v.x : 0.f;
    v.y = v.y > 0.f ? v.y : 0.f;
    v.z = v.z > 0.f ? v.z : 0.f;
    v.w = v.w > 0.f ? v.w : 0.f;
    ((float4*)out)[i] = v;
  }
}

// ---------------- launch ----------------
extern "C" void kernel_launch(void* const* d_in, const int* in_sizes, int n_in,
                              void* d_out, int out_size, void* d_ws,
                              size_t ws_size, hipStream_t stream) {
  const float* x = (const float*)d_in[0];
  const float* W = (const float*)d_in[1];
  const float* ev = (const float*)d_in[2];
  const int* esrc = (const int*)d_in[3];
  const int* edst = (const int*)d_in[4];

  const int n_nodes = in_sizes[0] / D_IN;
  const int n_edges = in_sizes[2];
  const int64_t n_out = (int64_t)n_nodes * D_OUT;
  const int n_bins = (n_nodes + BIN_NODES - 1) >> BIN_SHIFT;
  const int n_row_tiles = (n_nodes + 63) / 64;

  float* out = (float*)d_out;

  // workspace layout
  char* w = (char*)d_ws;
  ushort* pre16 = (ushort*)w;             w += (size_t)n_nodes * D_OUT * 2;
  int* bin_cursor = (int*)w;              w += (size_t)n_bins * 4;
  float* stats = (float*)w;               w += 128 * 4;
  w = (char*)(((uintptr_t)w + 7) & ~(uintptr_t)7);
  uint2* bucket = (uint2*)w;              // n_bins * BIN_CAP * 8 bytes (~32 MB)

  hipMemsetAsync(bin_cursor, 0, (size_t)n_bins * 4, stream);
  hipMemsetAsync(stats, 0, 128 * 4, stream);

  gemm_mfma_kernel<<<(n_row_tiles + 1) / 2, 256, 0, stream>>>(
      x, W, pre16, n_nodes, n_row_tiles);
  partition_kernel<<<(n_edges + CHUNK - 1) / CHUNK, 256, 0, stream>>>(
      ev, esrc, edst, bin_cursor, bucket, n_edges, n_bins);
  bin_sort_gather_kernel<<<4 * n_bins, 256, 0, stream>>>(
      pre16, bucket, bin_cursor, out, stats, n_nodes, n_bins);
  norm_kernel<<<2048, 256, 0, stream>>>(out, stats, n_out / 4,
                                        1.0f / (float)n_nodes);
}

// Round 2
// 312.223 us; speedup vs baseline: 1.2216x; 1.2216x over previous
//
#include <hip/hip_runtime.h>
#include <stdint.h>

#define D_IN  128
#define D_OUT 64
#define BN_EPS 1e-3f

#define BIN_SHIFT 6
#define BIN_NODES 64           // 1 << BIN_SHIFT
#define BIN_CAP   2560         // avg 2048 records/bin, +11 sigma headroom
#define CHUNK     8192         // edges per partition block (391 blocks)
#define MAX_BINS  1600

typedef __attribute__((ext_vector_type(8))) short bf16x8;
typedef __attribute__((ext_vector_type(4))) float f32x4;

__device__ __forceinline__ ushort f32_to_bf16_rne(float f) {
  uint u = __float_as_uint(f);
  u += 0x7FFFu + ((u >> 16) & 1u);
  return (ushort)(u >> 16);
}
__device__ __forceinline__ float bf16_to_f32(ushort h) {
  return __uint_as_float((uint)h << 16);
}

// ------------- GEMM via MFMA: pre16 = bf16(X @ W), bf16 in / fp32 acc -------
// Row-major pre16[row][64ch]: one node = one 128-B cache line. This is
// load-bearing for the gather kernel (round-1 lesson: slab layouts over-fetch
// 4x on random access).
__global__ __launch_bounds__(256) void gemm_mfma_kernel(
    const float* __restrict__ x, const float* __restrict__ W,
    ushort* __restrict__ pre16, int n_nodes, int n_tiles) {
  __shared__ ushort Wb[D_IN * D_OUT];  // 16 KB bf16 copy of W
  const int t = threadIdx.x;
  for (int i = t; i < D_IN * D_OUT; i += 256) Wb[i] = f32_to_bf16_rne(W[i]);
  __syncthreads();

  const int lane = t & 63;
  const int wave = t >> 6;
  const int m = lane & 15;
  const int quad = lane >> 4;

  bf16x8 bfrag[4][4];
#pragma unroll
  for (int nt = 0; nt < 4; ++nt)
#pragma unroll
    for (int s = 0; s < 4; ++s)
#pragma unroll
      for (int j = 0; j < 8; ++j)
        bfrag[nt][s][j] =
            (short)Wb[(32 * s + quad * 8 + j) * D_OUT + nt * 16 + m];

  for (int tile = blockIdx.x; tile < n_tiles; tile += gridDim.x) {
    const int rbase = tile * 64 + wave * 16;
    const int row = rbase + m;
    const size_t rl = (size_t)min(row, n_nodes - 1);
    f32x4 acc0 = {0.f, 0.f, 0.f, 0.f}, acc1 = {0.f, 0.f, 0.f, 0.f};
    f32x4 acc2 = {0.f, 0.f, 0.f, 0.f}, acc3 = {0.f, 0.f, 0.f, 0.f};
#pragma unroll
    for (int s = 0; s < 4; ++s) {
      const float4 xa = *(const float4*)&x[rl * D_IN + s * 32 + quad * 8];
      const float4 xb = *(const float4*)&x[rl * D_IN + s * 32 + quad * 8 + 4];
      bf16x8 af;
      af[0] = (short)f32_to_bf16_rne(xa.x);
      af[1] = (short)f32_to_bf16_rne(xa.y);
      af[2] = (short)f32_to_bf16_rne(xa.z);
      af[3] = (short)f32_to_bf16_rne(xa.w);
      af[4] = (short)f32_to_bf16_rne(xb.x);
      af[5] = (short)f32_to_bf16_rne(xb.y);
      af[6] = (short)f32_to_bf16_rne(xb.z);
      af[7] = (short)f32_to_bf16_rne(xb.w);
      acc0 = __builtin_amdgcn_mfma_f32_16x16x32_bf16(af, bfrag[0][s], acc0, 0, 0, 0);
      acc1 = __builtin_amdgcn_mfma_f32_16x16x32_bf16(af, bfrag[1][s], acc1, 0, 0, 0);
      acc2 = __builtin_amdgcn_mfma_f32_16x16x32_bf16(af, bfrag[2][s], acc2, 0, 0, 0);
      acc3 = __builtin_amdgcn_mfma_f32_16x16x32_bf16(af, bfrag[3][s], acc3, 0, 0, 0);
    }
#pragma unroll
    for (int reg = 0; reg < 4; ++reg) {
      const int r = rbase + quad * 4 + reg;
      if (r < n_nodes) {
        ushort* po = &pre16[(size_t)r * D_OUT + m];
        po[0]  = f32_to_bf16_rne(acc0[reg]);
        po[16] = f32_to_bf16_rne(acc1[reg]);
        po[32] = f32_to_bf16_rne(acc2[reg]);
        po[48] = f32_to_bf16_rne(acc3[reg]);
      }
    }
  }
}

// ---------------- Partition: bin edges by dst>>6, x4-vectorized loads ---------
// record: w0 = (dst_low6 << 17) | src17 ; w1 = fp32 edge_val
__global__ __launch_bounds__(256) void partition_kernel(
    const float* __restrict__ ev, const int* __restrict__ esrc,
    const int* __restrict__ edst, int* __restrict__ bin_cursor,
    uint2* __restrict__ bucket, int n_edges, int n_bins) {
  __shared__ int cnt[MAX_BINS];
  __shared__ int base[MAX_BINS];
  const int t = threadIdx.x;
  const int beg = blockIdx.x * CHUNK;
  const int end = min(beg + CHUNK, n_edges);

  for (int i = t; i < n_bins; i += 256) cnt[i] = 0;
  __syncthreads();

  // phase A: histogram, 4 edges per lane per load (1 KB/wave coalesced)
  for (int i = beg + t * 4; i < end; i += 1024) {
    if (i + 3 < end) {
      const int4 d4 = *(const int4*)&edst[i];
      atomicAdd(&cnt[d4.x >> BIN_SHIFT], 1);
      atomicAdd(&cnt[d4.y >> BIN_SHIFT], 1);
      atomicAdd(&cnt[d4.z >> BIN_SHIFT], 1);
      atomicAdd(&cnt[d4.w >> BIN_SHIFT], 1);
    } else {
      for (int k = i; k < end; ++k) atomicAdd(&cnt[edst[k] >> BIN_SHIFT], 1);
    }
  }
  __syncthreads();

  // phase B: reserve contiguous space per (block, bin)
  for (int i = t; i < n_bins; i += 256) {
    const int c = cnt[i];
    int b = 0;
    if (c > 0) b = atomicAdd(&bin_cursor[i], c);
    if (b > BIN_CAP) b = BIN_CAP;
    base[i] = i * BIN_CAP + b;
    cnt[i] = 0;  // reuse as rank cursor
  }
  __syncthreads();

  // phase C: scatter records (re-reads are L2-hot from phase A)
  for (int i = beg + t * 4; i < end; i += 1024) {
    if (i + 3 < end) {
      const int4 d4 = *(const int4*)&edst[i];
      const int4 s4 = *(const int4*)&esrc[i];
      const float4 v4 = *(const float4*)&ev[i];
#pragma unroll
      for (int k = 0; k < 4; ++k) {
        const int dst = (&d4.x)[k];
        const int src = (&s4.x)[k];
        const float v = (&v4.x)[k];
        const int bin = dst >> BIN_SHIFT;
        const int r = atomicAdd(&cnt[bin], 1);
        const int pos = base[bin] + r;
        if (pos < (bin + 1) * BIN_CAP) {
          const uint w0 = ((uint)(dst & (BIN_NODES - 1)) << 17) | (uint)src;
          bucket[pos] = make_uint2(w0, __float_as_uint(v));
        }
      }
    } else {
      for (int k = i; k < end; ++k) {
        const int dst = edst[k];
        const int bin = dst >> BIN_SHIFT;
        const int r = atomicAdd(&cnt[bin], 1);
        const int pos = base[bin] + r;
        if (pos < (bin + 1) * BIN_CAP) {
          const uint w0 = ((uint)(dst & (BIN_NODES - 1)) << 17) | (uint)esrc[k];
          bucket[pos] = make_uint2(w0, __float_as_uint(ev[k]));
        }
      }
    }
  }
}

// ------- Bin sort+gather: LDS counting sort, half-wave gather ----------------
// Latency-bound on random pre16 line reads (L2/L3 hit latency); the lever is
// memory-level parallelism: 8 independent gather loads in flight per
// half-wave (was 4). VGPR headroom is large (24 -> ~60), occupancy is
// LDS-capped so unaffected.
__global__ __launch_bounds__(256) void bin_sort_gather_kernel(
    const ushort* __restrict__ pre16, const uint2* __restrict__ bucket,
    const int* __restrict__ bin_cursor, float* __restrict__ out,
    float* __restrict__ stats, int n_nodes) {
  __shared__ uint s_src[BIN_CAP];          // 10.0 KB
  __shared__ ushort s_val[BIN_CAP];        // 5.0 KB
  __shared__ int s_hist[BIN_NODES];
  __shared__ int s_off[BIN_NODES + 1];
  __shared__ int s_cur[BIN_NODES];

  const int t = threadIdx.x;
  const int bin = blockIdx.x;
  const int cnt = min(bin_cursor[bin], BIN_CAP);
  const int64_t rbase = (int64_t)bin * BIN_CAP;

  if (t < BIN_NODES) s_hist[t] = 0;
  __syncthreads();

  for (int i = t; i < cnt; i += 256)
    atomicAdd(&s_hist[bucket[rbase + i].x >> 17], 1);
  __syncthreads();

  int own = (t < BIN_NODES) ? s_hist[t] : 0;
  for (int off = 1; off < BIN_NODES; off <<= 1) {
    int u = 0;
    if (t < BIN_NODES && t >= off) u = s_hist[t - off];
    __syncthreads();
    if (t < BIN_NODES) s_hist[t] += u;
    __syncthreads();
  }
  if (t < BIN_NODES) {
    const int e = s_hist[t] - own;
    s_off[t] = e;
    s_cur[t] = e;
  }
  if (t == 0) s_off[BIN_NODES] = cnt;
  __syncthreads();

  for (int i = t; i < cnt; i += 256) {
    const uint2 r = bucket[rbase + i];
    const int d = r.x >> 17;
    const int p = atomicAdd(&s_cur[d], 1);
    s_src[p] = r.x & 0x1FFFFu;
    s_val[p] = f32_to_bf16_rne(__uint_as_float(r.y));
  }
  __syncthreads();

  // gather: wave per node; half-waves on even/odd records; 8 records/half in
  // flight in the main loop, 4 in the mid loop, 1 in the tail.
  const int lane = t & 63;
  const int wave = t >> 6;
  const int half = lane >> 5;
  const int hl = lane & 31;
  const int node0 = bin * BIN_NODES;
  float csx = 0.f, csy = 0.f, cs2x = 0.f, cs2y = 0.f;

  for (int nl = wave; nl < BIN_NODES; nl += 4) {
    const int node = node0 + nl;
    if (node < n_nodes) {
      const int jb = s_off[nl], je = s_off[nl + 1];
      float a0x = 0.f, a0y = 0.f, a1x = 0.f, a1y = 0.f;
      float a2x = 0.f, a2y = 0.f, a3x = 0.f, a3y = 0.f;
      float a4x = 0.f, a4y = 0.f, a5x = 0.f, a5y = 0.f;
      float a6x = 0.f, a6y = 0.f, a7x = 0.f, a7y = 0.f;
      int j = jb + half;
      // main: 16 records per wave-iteration, 8 loads in flight per half
      for (; j + 14 < je; j += 16) {
        const uint src0 = s_src[j],      src1 = s_src[j + 2];
        const uint src2 = s_src[j + 4],  src3 = s_src[j + 6];
        const uint src4 = s_src[j + 8],  src5 = s_src[j + 10];
        const uint src6 = s_src[j + 12], src7 = s_src[j + 14];
        const float v0 = bf16_to_f32(s_val[j]);
        const float v1 = bf16_to_f32(s_val[j + 2]);
        const float v2 = bf16_to_f32(s_val[j + 4]);
        const float v3 = bf16_to_f32(s_val[j + 6]);
        const float v4 = bf16_to_f32(s_val[j + 8]);
        const float v5 = bf16_to_f32(s_val[j + 10]);
        const float v6 = bf16_to_f32(s_val[j + 12]);
        const float v7 = bf16_to_f32(s_val[j + 14]);
        const uint p0 = *(const uint*)&pre16[(size_t)src0 * D_OUT + 2 * hl];
        const uint p1 = *(const uint*)&pre16[(size_t)src1 * D_OUT + 2 * hl];
        const uint p2 = *(const uint*)&pre16[(size_t)src2 * D_OUT + 2 * hl];
        const uint p3 = *(const uint*)&pre16[(size_t)src3 * D_OUT + 2 * hl];
        const uint p4 = *(const uint*)&pre16[(size_t)src4 * D_OUT + 2 * hl];
        const uint p5 = *(const uint*)&pre16[(size_t)src5 * D_OUT + 2 * hl];
        const uint p6 = *(const uint*)&pre16[(size_t)src6 * D_OUT + 2 * hl];
        const uint p7 = *(const uint*)&pre16[(size_t)src7 * D_OUT + 2 * hl];
        a0x += v0 * bf16_to_f32((ushort)(p0 & 0xFFFFu));
        a0y += v0 * bf16_to_f32((ushort)(p0 >> 16));
        a1x += v1 * bf16_to_f32((ushort)(p1 & 0xFFFFu));
        a1y += v1 * bf16_to_f32((ushort)(p1 >> 16));
        a2x += v2 * bf16_to_f32((ushort)(p2 & 0xFFFFu));
        a2y += v2 * bf16_to_f32((ushort)(p2 >> 16));
        a3x += v3 * bf16_to_f32((ushort)(p3 & 0xFFFFu));
        a3y += v3 * bf16_to_f32((ushort)(p3 >> 16));
        a4x += v4 * bf16_to_f32((ushort)(p4 & 0xFFFFu));
        a4y += v4 * bf16_to_f32((ushort)(p4 >> 16));
        a5x += v5 * bf16_to_f32((ushort)(p5 & 0xFFFFu));
        a5y += v5 * bf16_to_f32((ushort)(p5 >> 16));
        a6x += v6 * bf16_to_f32((ushort)(p6 & 0xFFFFu));
        a6y += v6 * bf16_to_f32((ushort)(p6 >> 16));
        a7x += v7 * bf16_to_f32((ushort)(p7 & 0xFFFFu));
        a7y += v7 * bf16_to_f32((ushort)(p7 >> 16));
      }
      // mid: 8 records per wave-iteration, 4 loads in flight per half
      for (; j + 6 < je; j += 8) {
        const uint src0 = s_src[j],     src1 = s_src[j + 2];
        const uint src2 = s_src[j + 4], src3 = s_src[j + 6];
        const float v0 = bf16_to_f32(s_val[j]);
        const float v1 = bf16_to_f32(s_val[j + 2]);
        const float v2 = bf16_to_f32(s_val[j + 4]);
        const float v3 = bf16_to_f32(s_val[j + 6]);
        const uint p0 = *(const uint*)&pre16[(size_t)src0 * D_OUT + 2 * hl];
        const uint p1 = *(const uint*)&pre16[(size_t)src1 * D_OUT + 2 * hl];
        const uint p2 = *(const uint*)&pre16[(size_t)src2 * D_OUT + 2 * hl];
        const uint p3 = *(const uint*)&pre16[(size_t)src3 * D_OUT + 2 * hl];
        a0x += v0 * bf16_to_f32((ushort)(p0 & 0xFFFFu));
        a0y += v0 * bf16_to_f32((ushort)(p0 >> 16));
        a1x += v1 * bf16_to_f32((ushort)(p1 & 0xFFFFu));
        a1y += v1 * bf16_to_f32((ushort)(p1 >> 16));
        a2x += v2 * bf16_to_f32((ushort)(p2 & 0xFFFFu));
        a2y += v2 * bf16_to_f32((ushort)(p2 >> 16));
        a3x += v3 * bf16_to_f32((ushort)(p3 & 0xFFFFu));
        a3y += v3 * bf16_to_f32((ushort)(p3 >> 16));
      }
      for (; j < je; j += 2) {
        const uint src = s_src[j];
        const float v = bf16_to_f32(s_val[j]);
        const uint p = *(const uint*)&pre16[(size_t)src * D_OUT + 2 * hl];
        a0x += v * bf16_to_f32((ushort)(p & 0xFFFFu));
        a0y += v * bf16_to_f32((ushort)(p >> 16));
      }
      float ax = ((a0x + a1x) + (a2x + a3x)) + ((a4x + a5x) + (a6x + a7x));
      float ay = ((a0y + a1y) + (a2y + a3y)) + ((a4y + a5y) + (a6y + a7y));
      ax += __shfl_xor(ax, 32);   // merge odd-record half into even half
      ay += __shfl_xor(ay, 32);
      if (half == 0) {
        *(float2*)&out[(size_t)node * D_OUT + 2 * hl] = make_float2(ax, ay);
        csx += ax;
        cs2x += ax * ax;
        csy += ay;
        cs2y += ay * ay;
      }
    }
  }
  __syncthreads();  // record reads done; alias reduction buffers onto s_src

  float* red = (float*)s_src;       // [4 waves][64 cols] sums
  float* red2 = red + 256;          // [4 waves][64 cols] sumsq
  if (half == 0) {
    red[wave * 64 + 2 * hl] = csx;
    red[wave * 64 + 2 * hl + 1] = csy;
    red2[wave * 64 + 2 * hl] = cs2x;
    red2[wave * 64 + 2 * hl + 1] = cs2y;
  }
  __syncthreads();
  if (t < 64) {
    float s = red[t] + red[64 + t] + red[128 + t] + red[192 + t];
    float s2 = red2[t] + red2[64 + t] + red2[128 + t] + red2[192 + t];
    atomicAdd(&stats[t], s);
    atomicAdd(&stats[64 + t], s2);
  }
}

// ---------------- Normalize + ReLU (in place, float4) ----------------
__global__ __launch_bounds__(256) void norm_kernel(
    float* __restrict__ out, const float* __restrict__ stats, int64_t n_vec4,
    float inv_n) {
  const int c = (threadIdx.x * 4) & 63;
  float mean[4], scale[4];
#pragma unroll
  for (int k = 0; k < 4; ++k) {
    mean[k] = stats[c + k] * inv_n;
    const float var = stats[64 + c + k] * inv_n - mean[k] * mean[k];
    scale[k] = rsqrtf(var + BN_EPS);
  }
  const int64_t stride = (int64_t)gridDim.x * 256;
  for (int64_t i = (int64_t)blockIdx.x * 256 + threadIdx.x; i < n_vec4;
       i += stride) {
    float4 v = ((float4*)out)[i];
    v.x = (v.x - mean[0]) * scale[0];
    v.y = (v.y - mean[1]) * scale[1];
    v.z = (v.z - mean[2]) * scale[2];
    v.w = (v.w - mean[3]) * scale[3];
    v.x = v.x > 0.f ? v.x : 0.f;
    v.y = v.y > 0.f ? v.y : 0.f;
    v.z = v.z > 0.f ? v.z : 0.f;
    v.w = v.w > 0.f ? v.w : 0.f;
    ((float4*)out)[i] = v;
  }
}

// ---------------- launch ----------------
extern "C" void kernel_launch(void* const* d_in, const int* in_sizes, int n_in,
                              void* d_out, int out_size, void* d_ws,
                              size_t ws_size, hipStream_t stream) {
  const float* x = (const float*)d_in[0];
  const float* W = (const float*)d_in[1];
  const float* ev = (const float*)d_in[2];
  const int* esrc = (const int*)d_in[3];
  const int* edst = (const int*)d_in[4];

  const int n_nodes = in_sizes[0] / D_IN;
  const int n_edges = in_sizes[2];
  const int64_t n_out = (int64_t)n_nodes * D_OUT;
  const int n_bins = (n_nodes + BIN_NODES - 1) >> BIN_SHIFT;
  const int n_row_tiles = (n_nodes + 63) / 64;

  float* out = (float*)d_out;

  // workspace layout
  char* w = (char*)d_ws;
  ushort* pre16 = (ushort*)w;             w += (size_t)n_nodes * D_OUT * 2;
  int* bin_cursor = (int*)w;              w += (size_t)n_bins * 4;
  float* stats = (float*)w;               w += 128 * 4;
  w = (char*)(((uintptr_t)w + 7) & ~(uintptr_t)7);
  uint2* bucket = (uint2*)w;              // n_bins * BIN_CAP * 8 bytes (~32 MB)

  hipMemsetAsync(bin_cursor, 0, (size_t)n_bins * 4, stream);
  hipMemsetAsync(stats, 0, 128 * 4, stream);

  gemm_mfma_kernel<<<(n_row_tiles + 1) / 2, 256, 0, stream>>>(
      x, W, pre16, n_nodes, n_row_tiles);
  partition_kernel<<<(n_edges + CHUNK - 1) / CHUNK, 256, 0, stream>>>(
      ev, esrc, edst, bin_cursor, bucket, n_edges, n_bins);
  bin_sort_gather_kernel<<<n_bins, 256, 0, stream>>>(pre16, bucket, bin_cursor,
                                                     out, stats, n_nodes);
  norm_kernel<<<2048, 256, 0, stream>>>(out, stats, n_out / 4,
                                        1.0f / (float)n_nodes);
}

// Round 3
// 308.511 us; speedup vs baseline: 1.2363x; 1.0120x over previous
//
#include <hip/hip_runtime.h>
#include <stdint.h>

#define D_IN  128
#define D_OUT 64
#define BN_EPS 1e-3f

#define BIN_SHIFT 6
#define BIN_NODES 64           // 1 << BIN_SHIFT
#define BIN_CAP   2560         // avg 2048 records/bin, +11 sigma headroom
#define CHUNK     8192         // edges per partition block (391 blocks)
#define MAX_BINS  1600

typedef __attribute__((ext_vector_type(8))) short bf16x8;
typedef __attribute__((ext_vector_type(4))) float f32x4;

__device__ __forceinline__ ushort f32_to_bf16_rne(float f) {
  uint u = __float_as_uint(f);
  u += 0x7FFFu + ((u >> 16) & 1u);
  return (ushort)(u >> 16);
}
__device__ __forceinline__ float bf16_to_f32(ushort h) {
  return __uint_as_float((uint)h << 16);
}

// ------------- GEMM via MFMA: pre16 = bf16(X @ W), bf16 in / fp32 acc -------
// Row-major pre16[row][64ch]: one node = one 128-B cache line (load-bearing
// for the gather; slab layouts over-fetch 4x on random access — round 1).
__global__ __launch_bounds__(256) void gemm_mfma_kernel(
    const float* __restrict__ x, const float* __restrict__ W,
    ushort* __restrict__ pre16, int n_nodes, int n_tiles) {
  __shared__ ushort Wb[D_IN * D_OUT];  // 16 KB bf16 copy of W
  const int t = threadIdx.x;
  for (int i = t; i < D_IN * D_OUT; i += 256) Wb[i] = f32_to_bf16_rne(W[i]);
  __syncthreads();

  const int lane = t & 63;
  const int wave = t >> 6;
  const int m = lane & 15;
  const int quad = lane >> 4;

  bf16x8 bfrag[4][4];
#pragma unroll
  for (int nt = 0; nt < 4; ++nt)
#pragma unroll
    for (int s = 0; s < 4; ++s)
#pragma unroll
      for (int j = 0; j < 8; ++j)
        bfrag[nt][s][j] =
            (short)Wb[(32 * s + quad * 8 + j) * D_OUT + nt * 16 + m];

  for (int tile = blockIdx.x; tile < n_tiles; tile += gridDim.x) {
    const int rbase = tile * 64 + wave * 16;
    const int row = rbase + m;
    const size_t rl = (size_t)min(row, n_nodes - 1);
    f32x4 acc0 = {0.f, 0.f, 0.f, 0.f}, acc1 = {0.f, 0.f, 0.f, 0.f};
    f32x4 acc2 = {0.f, 0.f, 0.f, 0.f}, acc3 = {0.f, 0.f, 0.f, 0.f};
#pragma unroll
    for (int s = 0; s < 4; ++s) {
      const float4 xa = *(const float4*)&x[rl * D_IN + s * 32 + quad * 8];
      const float4 xb = *(const float4*)&x[rl * D_IN + s * 32 + quad * 8 + 4];
      bf16x8 af;
      af[0] = (short)f32_to_bf16_rne(xa.x);
      af[1] = (short)f32_to_bf16_rne(xa.y);
      af[2] = (short)f32_to_bf16_rne(xa.z);
      af[3] = (short)f32_to_bf16_rne(xa.w);
      af[4] = (short)f32_to_bf16_rne(xb.x);
      af[5] = (short)f32_to_bf16_rne(xb.y);
      af[6] = (short)f32_to_bf16_rne(xb.z);
      af[7] = (short)f32_to_bf16_rne(xb.w);
      acc0 = __builtin_amdgcn_mfma_f32_16x16x32_bf16(af, bfrag[0][s], acc0, 0, 0, 0);
      acc1 = __builtin_amdgcn_mfma_f32_16x16x32_bf16(af, bfrag[1][s], acc1, 0, 0, 0);
      acc2 = __builtin_amdgcn_mfma_f32_16x16x32_bf16(af, bfrag[2][s], acc2, 0, 0, 0);
      acc3 = __builtin_amdgcn_mfma_f32_16x16x32_bf16(af, bfrag[3][s], acc3, 0, 0, 0);
    }
#pragma unroll
    for (int reg = 0; reg < 4; ++reg) {
      const int r = rbase + quad * 4 + reg;
      if (r < n_nodes) {
        ushort* po = &pre16[(size_t)r * D_OUT + m];
        po[0]  = f32_to_bf16_rne(acc0[reg]);
        po[16] = f32_to_bf16_rne(acc1[reg]);
        po[32] = f32_to_bf16_rne(acc2[reg]);
        po[48] = f32_to_bf16_rne(acc3[reg]);
      }
    }
  }
}

// ---------------- Partition: bin edges by dst>>6, x4-vectorized loads ---------
// record: w0 = (dst_low6 << 17) | src17 ; w1 = fp32 edge_val
__global__ __launch_bounds__(256) void partition_kernel(
    const float* __restrict__ ev, const int* __restrict__ esrc,
    const int* __restrict__ edst, int* __restrict__ bin_cursor,
    uint2* __restrict__ bucket, int n_edges, int n_bins) {
  __shared__ int cnt[MAX_BINS];
  __shared__ int base[MAX_BINS];
  const int t = threadIdx.x;
  const int beg = blockIdx.x * CHUNK;
  const int end = min(beg + CHUNK, n_edges);

  for (int i = t; i < n_bins; i += 256) cnt[i] = 0;
  __syncthreads();

  // phase A: histogram, 4 edges per lane per load (1 KB/wave coalesced)
  for (int i = beg + t * 4; i < end; i += 1024) {
    if (i + 3 < end) {
      const int4 d4 = *(const int4*)&edst[i];
      atomicAdd(&cnt[d4.x >> BIN_SHIFT], 1);
      atomicAdd(&cnt[d4.y >> BIN_SHIFT], 1);
      atomicAdd(&cnt[d4.z >> BIN_SHIFT], 1);
      atomicAdd(&cnt[d4.w >> BIN_SHIFT], 1);
    } else {
      for (int k = i; k < end; ++k) atomicAdd(&cnt[edst[k] >> BIN_SHIFT], 1);
    }
  }
  __syncthreads();

  // phase B: reserve contiguous space per (block, bin)
  for (int i = t; i < n_bins; i += 256) {
    const int c = cnt[i];
    int b = 0;
    if (c > 0) b = atomicAdd(&bin_cursor[i], c);
    if (b > BIN_CAP) b = BIN_CAP;
    base[i] = i * BIN_CAP + b;
    cnt[i] = 0;  // reuse as rank cursor
  }
  __syncthreads();

  // phase C: scatter records (re-reads are L2-hot from phase A)
  for (int i = beg + t * 4; i < end; i += 1024) {
    if (i + 3 < end) {
      const int4 d4 = *(const int4*)&edst[i];
      const int4 s4 = *(const int4*)&esrc[i];
      const float4 v4 = *(const float4*)&ev[i];
#pragma unroll
      for (int k = 0; k < 4; ++k) {
        const int dst = (&d4.x)[k];
        const int src = (&s4.x)[k];
        const float v = (&v4.x)[k];
        const int bin = dst >> BIN_SHIFT;
        const int r = atomicAdd(&cnt[bin], 1);
        const int pos = base[bin] + r;
        if (pos < (bin + 1) * BIN_CAP) {
          const uint w0 = ((uint)(dst & (BIN_NODES - 1)) << 17) | (uint)src;
          bucket[pos] = make_uint2(w0, __float_as_uint(v));
        }
      }
    } else {
      for (int k = i; k < end; ++k) {
        const int dst = edst[k];
        const int bin = dst >> BIN_SHIFT;
        const int r = atomicAdd(&cnt[bin], 1);
        const int pos = base[bin] + r;
        if (pos < (bin + 1) * BIN_CAP) {
          const uint w0 = ((uint)(dst & (BIN_NODES - 1)) << 17) | (uint)esrc[k];
          bucket[pos] = make_uint2(w0, __float_as_uint(ev[k]));
        }
      }
    }
  }
}

// ------- Bin sort+gather: LDS counting sort, half-wave gather ----------------
// Latency-bound; round-2 lesson: ILP depth beyond 8 loads barely helps — the
// binding cap was thread-level parallelism (grid 1563 x 4 waves = 24 waves/CU
// max -> 44% occupancy). This version: 512-thread blocks (8 waves). LDS stays
// 16 KB, so residency is wave-slot-capped: 4 blocks x 8 waves = 32 waves/CU
// while >=4 blocks/CU remain -> ~2x resident waves at identical per-edge work.
__global__ __launch_bounds__(512) void bin_sort_gather_kernel(
    const ushort* __restrict__ pre16, const uint2* __restrict__ bucket,
    const int* __restrict__ bin_cursor, float* __restrict__ out,
    float* __restrict__ stats, int n_nodes) {
  __shared__ uint s_src[BIN_CAP];          // 10.0 KB
  __shared__ ushort s_val[BIN_CAP];        // 5.0 KB
  __shared__ int s_hist[BIN_NODES];
  __shared__ int s_off[BIN_NODES + 1];
  __shared__ int s_cur[BIN_NODES];

  const int t = threadIdx.x;
  const int bin = blockIdx.x;
  const int cnt = min(bin_cursor[bin], BIN_CAP);
  const int64_t rbase = (int64_t)bin * BIN_CAP;

  if (t < BIN_NODES) s_hist[t] = 0;
  __syncthreads();

  for (int i = t; i < cnt; i += 512)
    atomicAdd(&s_hist[bucket[rbase + i].x >> 17], 1);
  __syncthreads();

  int own = (t < BIN_NODES) ? s_hist[t] : 0;
  for (int off = 1; off < BIN_NODES; off <<= 1) {
    int u = 0;
    if (t < BIN_NODES && t >= off) u = s_hist[t - off];
    __syncthreads();
    if (t < BIN_NODES) s_hist[t] += u;
    __syncthreads();
  }
  if (t < BIN_NODES) {
    const int e = s_hist[t] - own;
    s_off[t] = e;
    s_cur[t] = e;
  }
  if (t == 0) s_off[BIN_NODES] = cnt;
  __syncthreads();

  for (int i = t; i < cnt; i += 512) {
    const uint2 r = bucket[rbase + i];
    const int d = r.x >> 17;
    const int p = atomicAdd(&s_cur[d], 1);
    s_src[p] = r.x & 0x1FFFFu;
    s_val[p] = f32_to_bf16_rne(__uint_as_float(r.y));
  }
  __syncthreads();

  // gather: wave per node (8 waves -> 8 nodes in flight); half-waves on
  // even/odd records; 8 records/half in flight in the main loop.
  const int lane = t & 63;
  const int wave = t >> 6;
  const int half = lane >> 5;
  const int hl = lane & 31;
  const int node0 = bin * BIN_NODES;
  float csx = 0.f, csy = 0.f, cs2x = 0.f, cs2y = 0.f;

  for (int nl = wave; nl < BIN_NODES; nl += 8) {
    const int node = node0 + nl;
    if (node < n_nodes) {
      const int jb = s_off[nl], je = s_off[nl + 1];
      float a0x = 0.f, a0y = 0.f, a1x = 0.f, a1y = 0.f;
      float a2x = 0.f, a2y = 0.f, a3x = 0.f, a3y = 0.f;
      float a4x = 0.f, a4y = 0.f, a5x = 0.f, a5y = 0.f;
      float a6x = 0.f, a6y = 0.f, a7x = 0.f, a7y = 0.f;
      int j = jb + half;
      // main: 16 records per wave-iteration, 8 loads in flight per half
      for (; j + 14 < je; j += 16) {
        const uint src0 = s_src[j],      src1 = s_src[j + 2];
        const uint src2 = s_src[j + 4],  src3 = s_src[j + 6];
        const uint src4 = s_src[j + 8],  src5 = s_src[j + 10];
        const uint src6 = s_src[j + 12], src7 = s_src[j + 14];
        const float v0 = bf16_to_f32(s_val[j]);
        const float v1 = bf16_to_f32(s_val[j + 2]);
        const float v2 = bf16_to_f32(s_val[j + 4]);
        const float v3 = bf16_to_f32(s_val[j + 6]);
        const float v4 = bf16_to_f32(s_val[j + 8]);
        const float v5 = bf16_to_f32(s_val[j + 10]);
        const float v6 = bf16_to_f32(s_val[j + 12]);
        const float v7 = bf16_to_f32(s_val[j + 14]);
        const uint p0 = *(const uint*)&pre16[(size_t)src0 * D_OUT + 2 * hl];
        const uint p1 = *(const uint*)&pre16[(size_t)src1 * D_OUT + 2 * hl];
        const uint p2 = *(const uint*)&pre16[(size_t)src2 * D_OUT + 2 * hl];
        const uint p3 = *(const uint*)&pre16[(size_t)src3 * D_OUT + 2 * hl];
        const uint p4 = *(const uint*)&pre16[(size_t)src4 * D_OUT + 2 * hl];
        const uint p5 = *(const uint*)&pre16[(size_t)src5 * D_OUT + 2 * hl];
        const uint p6 = *(const uint*)&pre16[(size_t)src6 * D_OUT + 2 * hl];
        const uint p7 = *(const uint*)&pre16[(size_t)src7 * D_OUT + 2 * hl];
        a0x += v0 * bf16_to_f32((ushort)(p0 & 0xFFFFu));
        a0y += v0 * bf16_to_f32((ushort)(p0 >> 16));
        a1x += v1 * bf16_to_f32((ushort)(p1 & 0xFFFFu));
        a1y += v1 * bf16_to_f32((ushort)(p1 >> 16));
        a2x += v2 * bf16_to_f32((ushort)(p2 & 0xFFFFu));
        a2y += v2 * bf16_to_f32((ushort)(p2 >> 16));
        a3x += v3 * bf16_to_f32((ushort)(p3 & 0xFFFFu));
        a3y += v3 * bf16_to_f32((ushort)(p3 >> 16));
        a4x += v4 * bf16_to_f32((ushort)(p4 & 0xFFFFu));
        a4y += v4 * bf16_to_f32((ushort)(p4 >> 16));
        a5x += v5 * bf16_to_f32((ushort)(p5 & 0xFFFFu));
        a5y += v5 * bf16_to_f32((ushort)(p5 >> 16));
        a6x += v6 * bf16_to_f32((ushort)(p6 & 0xFFFFu));
        a6y += v6 * bf16_to_f32((ushort)(p6 >> 16));
        a7x += v7 * bf16_to_f32((ushort)(p7 & 0xFFFFu));
        a7y += v7 * bf16_to_f32((ushort)(p7 >> 16));
      }
      // mid: 8 records per wave-iteration, 4 loads in flight per half
      for (; j + 6 < je; j += 8) {
        const uint src0 = s_src[j],     src1 = s_src[j + 2];
        const uint src2 = s_src[j + 4], src3 = s_src[j + 6];
        const float v0 = bf16_to_f32(s_val[j]);
        const float v1 = bf16_to_f32(s_val[j + 2]);
        const float v2 = bf16_to_f32(s_val[j + 4]);
        const float v3 = bf16_to_f32(s_val[j + 6]);
        const uint p0 = *(const uint*)&pre16[(size_t)src0 * D_OUT + 2 * hl];
        const uint p1 = *(const uint*)&pre16[(size_t)src1 * D_OUT + 2 * hl];
        const uint p2 = *(const uint*)&pre16[(size_t)src2 * D_OUT + 2 * hl];
        const uint p3 = *(const uint*)&pre16[(size_t)src3 * D_OUT + 2 * hl];
        a0x += v0 * bf16_to_f32((ushort)(p0 & 0xFFFFu));
        a0y += v0 * bf16_to_f32((ushort)(p0 >> 16));
        a1x += v1 * bf16_to_f32((ushort)(p1 & 0xFFFFu));
        a1y += v1 * bf16_to_f32((ushort)(p1 >> 16));
        a2x += v2 * bf16_to_f32((ushort)(p2 & 0xFFFFu));
        a2y += v2 * bf16_to_f32((ushort)(p2 >> 16));
        a3x += v3 * bf16_to_f32((ushort)(p3 & 0xFFFFu));
        a3y += v3 * bf16_to_f32((ushort)(p3 >> 16));
      }
      for (; j < je; j += 2) {
        const uint src = s_src[j];
        const float v = bf16_to_f32(s_val[j]);
        const uint p = *(const uint*)&pre16[(size_t)src * D_OUT + 2 * hl];
        a0x += v * bf16_to_f32((ushort)(p & 0xFFFFu));
        a0y += v * bf16_to_f32((ushort)(p >> 16));
      }
      float ax = ((a0x + a1x) + (a2x + a3x)) + ((a4x + a5x) + (a6x + a7x));
      float ay = ((a0y + a1y) + (a2y + a3y)) + ((a4y + a5y) + (a6y + a7y));
      ax += __shfl_xor(ax, 32);   // merge odd-record half into even half
      ay += __shfl_xor(ay, 32);
      if (half == 0) {
        *(float2*)&out[(size_t)node * D_OUT + 2 * hl] = make_float2(ax, ay);
        csx += ax;
        cs2x += ax * ax;
        csy += ay;
        cs2y += ay * ay;
      }
    }
  }
  __syncthreads();  // record reads done; alias reduction buffers onto s_src

  float* red = (float*)s_src;       // [8 waves][64 cols] sums (2 KB)
  float* red2 = red + 512;          // [8 waves][64 cols] sumsq (2 KB)
  if (half == 0) {
    red[wave * 64 + 2 * hl] = csx;
    red[wave * 64 + 2 * hl + 1] = csy;
    red2[wave * 64 + 2 * hl] = cs2x;
    red2[wave * 64 + 2 * hl + 1] = cs2y;
  }
  __syncthreads();
  if (t < 64) {
    float s = 0.f, s2 = 0.f;
#pragma unroll
    for (int wv = 0; wv < 8; ++wv) {
      s += red[wv * 64 + t];
      s2 += red2[wv * 64 + t];
    }
    atomicAdd(&stats[t], s);
    atomicAdd(&stats[64 + t], s2);
  }
}

// ---------------- Normalize + ReLU (in place, float4) ----------------
__global__ __launch_bounds__(256) void norm_kernel(
    float* __restrict__ out, const float* __restrict__ stats, int64_t n_vec4,
    float inv_n) {
  const int c = (threadIdx.x * 4) & 63;
  float mean[4], scale[4];
#pragma unroll
  for (int k = 0; k < 4; ++k) {
    mean[k] = stats[c + k] * inv_n;
    const float var = stats[64 + c + k] * inv_n - mean[k] * mean[k];
    scale[k] = rsqrtf(var + BN_EPS);
  }
  const int64_t stride = (int64_t)gridDim.x * 256;
  for (int64_t i = (int64_t)blockIdx.x * 256 + threadIdx.x; i < n_vec4;
       i += stride) {
    float4 v = ((float4*)out)[i];
    v.x = (v.x - mean[0]) * scale[0];
    v.y = (v.y - mean[1]) * scale[1];
    v.z = (v.z - mean[2]) * scale[2];
    v.w = (v.w - mean[3]) * scale[3];
    v.x = v.x > 0.f ? v.x : 0.f;
    v.y = v.y > 0.f ? v.y : 0.f;
    v.z = v.z > 0.f ? v.z : 0.f;
    v.w = v.w > 0.f ? v.w : 0.f;
    ((float4*)out)[i] = v;
  }
}

// ---------------- launch ----------------
extern "C" void kernel_launch(void* const* d_in, const int* in_sizes, int n_in,
                              void* d_out, int out_size, void* d_ws,
                              size_t ws_size, hipStream_t stream) {
  const float* x = (const float*)d_in[0];
  const float* W = (const float*)d_in[1];
  const float* ev = (const float*)d_in[2];
  const int* esrc = (const int*)d_in[3];
  const int* edst = (const int*)d_in[4];

  const int n_nodes = in_sizes[0] / D_IN;
  const int n_edges = in_sizes[2];
  const int64_t n_out = (int64_t)n_nodes * D_OUT;
  const int n_bins = (n_nodes + BIN_NODES - 1) >> BIN_SHIFT;
  const int n_row_tiles = (n_nodes + 63) / 64;

  float* out = (float*)d_out;

  // workspace layout
  char* w = (char*)d_ws;
  ushort* pre16 = (ushort*)w;             w += (size_t)n_nodes * D_OUT * 2;
  int* bin_cursor = (int*)w;              w += (size_t)n_bins * 4;
  float* stats = (float*)w;               w += 128 * 4;
  w = (char*)(((uintptr_t)w + 7) & ~(uintptr_t)7);
  uint2* bucket = (uint2*)w;              // n_bins * BIN_CAP * 8 bytes (~32 MB)

  hipMemsetAsync(bin_cursor, 0, (size_t)n_bins * 4, stream);
  hipMemsetAsync(stats, 0, 128 * 4, stream);

  gemm_mfma_kernel<<<(n_row_tiles + 1) / 2, 256, 0, stream>>>(
      x, W, pre16, n_nodes, n_row_tiles);
  partition_kernel<<<(n_edges + CHUNK - 1) / CHUNK, 256, 0, stream>>>(
      ev, esrc, edst, bin_cursor, bucket, n_edges, n_bins);
  bin_sort_gather_kernel<<<n_bins, 512, 0, stream>>>(pre16, bucket, bin_cursor,
                                                     out, stats, n_nodes);
  norm_kernel<<<2048, 256, 0, stream>>>(out, stats, n_out / 4,
                                        1.0f / (float)n_nodes);
}